// Round 3
// baseline (1640.218 us; speedup 1.0000x reference)
//
#include <hip/hip_runtime.h>
#include <math.h>

#define NS 65536
#define LAN 2048
#define FEA 128

constexpr float THRES = 0.0025f;
constexpr float FEPS  = 1e-12f;
constexpr int BM   = 32;    // rows per block
constexpr int MAXS = 160;   // survivors/row cap (theoretical max 399; observed ~2-4, P(>160)~0)

typedef _Float16 half8  __attribute__((ext_vector_type(8)));
typedef float    f32x4  __attribute__((ext_vector_type(4)));
typedef float    f32x2v __attribute__((ext_vector_type(2)));

// ---- prep: split W (fp32) into f16 high/low parts, row-major [2048][128] ----
__global__ void k_prep_w(const float* __restrict__ W,
                         _Float16* __restrict__ Wh, _Float16* __restrict__ Wl) {
    int i = blockIdx.x * 256 + threadIdx.x;          // 0..262143
    float w = W[i];
    _Float16 h = (_Float16)w;
    Wh[i] = h;
    Wl[i] = (_Float16)(w - (float)h);
}

// ---- cen[k] = mean_c W[c][k] ----
__global__ void k_cen(const float* __restrict__ W, float* __restrict__ cen) {
    __shared__ float sb[4];
    int k = blockIdx.x;          // 0..127
    int tid = threadIdx.x;       // 256
    float s = 0.f;
    for (int c = tid; c < LAN; c += 256) s += W[(size_t)c * FEA + k];
    #pragma unroll
    for (int off = 32; off >= 1; off >>= 1) s += __shfl_xor(s, off);
    if ((tid & 63) == 0) sb[tid >> 6] = s;
    __syncthreads();
    if (tid == 0) cen[k] = (sb[0] + sb[1] + sb[2] + sb[3]) * (1.0f / (float)LAN);
}

// ---- main fused kernel: 512 threads (8 waves), 32 rows x 2048 cols per block ----
// wave wv owns all 32 rows x cols [wv*256, wv*256+256)
// MFMA 16x16x32_f16, 3-term split. C-frag: row=(lane>>4)*4+r, col=lane&15.
__global__ __launch_bounds__(512, 2) void k_main(
    const float* __restrict__ X, const float* __restrict__ W,
    const _Float16* __restrict__ Wh, const _Float16* __restrict__ Wl,
    const float* __restrict__ cen,
    float* __restrict__ o_out, float* __restrict__ o_att,
    float* __restrict__ o_nl, float* __restrict__ o_nl2,
    float* __restrict__ o_col)
{
    __shared__ __align__(16) _Float16 s_ah[BM][FEA];    // 8 KB
    __shared__ __align__(16) _Float16 s_al[BM][FEA];    // 8 KB
    __shared__ __align__(16) float s_bounce[8][4][264]; // 33.8 KB (pad 264: 2-way-free writes)
    __shared__ int   s_scol[BM][MAXS];                  // 20 KB
    __shared__ float s_sval[BM][MAXS];                  // 20 KB
    __shared__ float s_red[8][BM];
    __shared__ float s_t1v[8][BM]; __shared__ int s_t1c[8][BM];
    __shared__ float s_t2v[8][BM]; __shared__ int s_t2c[8][BM];
    __shared__ float s_rmax[BM], s_rsinv[BM], s_Sinv[BM];
    __shared__ int   s_ind[BM], s_ind2[BM], s_cnt[BM];

    const int tid  = threadIdx.x;
    const int wv   = tid >> 6;      // wave 0..7
    const int lane = tid & 63;
    const int g    = lane >> 4;     // k-group / row-group-of-4 in frags
    const int m    = lane & 15;     // A row within tile / B col within tile
    const int row0 = blockIdx.x * BM;

    // ---- stage X tile as f16 split ----
    {
        const float4* xsrc = (const float4*)(X + (size_t)row0 * FEA);
        #pragma unroll
        for (int q = 0; q < 2; ++q) {
            int idx = tid + q * 512;           // float4 index 0..1023
            float4 v = xsrc[idx];
            int r = idx >> 5, c4 = (idx & 31) * 4;
            _Float16 h0 = (_Float16)v.x, h1 = (_Float16)v.y;
            _Float16 h2 = (_Float16)v.z, h3 = (_Float16)v.w;
            s_ah[r][c4+0] = h0; s_ah[r][c4+1] = h1; s_ah[r][c4+2] = h2; s_ah[r][c4+3] = h3;
            s_al[r][c4+0] = (_Float16)(v.x - (float)h0);
            s_al[r][c4+1] = (_Float16)(v.y - (float)h1);
            s_al[r][c4+2] = (_Float16)(v.z - (float)h2);
            s_al[r][c4+3] = (_Float16)(v.w - (float)h3);
        }
    }
    __syncthreads();

    // ---- A fragments ----
    half8 afh[2][4], afl[2][4];
    #pragma unroll
    for (int rt = 0; rt < 2; ++rt)
        #pragma unroll
        for (int kb = 0; kb < 4; ++kb) {
            afh[rt][kb] = *(const half8*)&s_ah[rt*16 + m][kb*32 + g*8];
            afl[rt][kb] = *(const half8*)&s_al[rt*16 + m][kb*32 + g*8];
        }

    f32x4 acc[2][16];
    #pragma unroll
    for (int rt = 0; rt < 2; ++rt)
        #pragma unroll
        for (int t = 0; t < 16; ++t) acc[rt][t] = (f32x4){0.f, 0.f, 0.f, 0.f};

    // ---- GEMM over 16 col-tiles; B-frags from global (L2-resident W) ----
    const _Float16* bh_base = Wh + (size_t)(wv*256 + m) * FEA + g*8;
    const _Float16* bl_base = Wl + (size_t)(wv*256 + m) * FEA + g*8;
    #pragma unroll 2
    for (int t = 0; t < 16; ++t) {
        const _Float16* bhp = bh_base + (size_t)t * 16 * FEA;
        const _Float16* blp = bl_base + (size_t)t * 16 * FEA;
        half8 bh[4], bl[4];
        #pragma unroll
        for (int kb = 0; kb < 4; ++kb) {
            bh[kb] = *(const half8*)(bhp + kb*32);
            bl[kb] = *(const half8*)(blp + kb*32);
        }
        #pragma unroll
        for (int kb = 0; kb < 4; ++kb)
            #pragma unroll
            for (int rt = 0; rt < 2; ++rt) {
                acc[rt][t] = __builtin_amdgcn_mfma_f32_16x16x32_f16(afh[rt][kb], bh[kb], acc[rt][t], 0, 0, 0);
                acc[rt][t] = __builtin_amdgcn_mfma_f32_16x16x32_f16(afl[rt][kb], bh[kb], acc[rt][t], 0, 0, 0);
                acc[rt][t] = __builtin_amdgcn_mfma_f32_16x16x32_f16(afh[rt][kb], bl[kb], acc[rt][t], 0, 0, 0);
            }
    }

    // lane's row for (rt, r): lr = rt*16 + g*4 + r ; col for t: wv*256 + t*16 + m

    // ---- row max ----
    #pragma unroll
    for (int rt = 0; rt < 2; ++rt)
        #pragma unroll
        for (int r = 0; r < 4; ++r) {
            float mx = acc[rt][0][r];
            #pragma unroll
            for (int t = 1; t < 16; ++t) mx = fmaxf(mx, acc[rt][t][r]);
            #pragma unroll
            for (int off = 8; off >= 1; off >>= 1) mx = fmaxf(mx, __shfl_xor(mx, off));
            if (m == 0) s_red[wv][rt*16 + g*4 + r] = mx;
        }
    __syncthreads();
    if (tid < BM) {
        float mx = s_red[0][tid];
        #pragma unroll
        for (int w = 1; w < 8; ++w) mx = fmaxf(mx, s_red[w][tid]);
        s_rmax[tid] = mx;
    }
    __syncthreads();

    // ---- exp + row sum (overwrite acc with exp) ----
    #pragma unroll
    for (int rt = 0; rt < 2; ++rt)
        #pragma unroll
        for (int r = 0; r < 4; ++r) {
            const float rm = s_rmax[rt*16 + g*4 + r];
            float s = 0.f;
            #pragma unroll
            for (int t = 0; t < 16; ++t) {
                float e = expf(acc[rt][t][r] - rm);
                acc[rt][t][r] = e; s += e;
            }
            #pragma unroll
            for (int off = 8; off >= 1; off >>= 1) s += __shfl_xor(s, off);
            if (m == 0) s_red[wv][rt*16 + g*4 + r] = s;
        }
    __syncthreads();
    if (tid < BM) {
        float s = s_red[0][tid];
        #pragma unroll
        for (int w = 1; w < 8; ++w) s += s_red[w][tid];
        s_rsinv[tid] = 1.0f / s;      // sum >= 1 always (max term is exp(0)=1)
        s_cnt[tid] = 0;
    }
    __syncthreads();

    // ---- shrink (overwrite acc), row S ----
    #pragma unroll
    for (int rt = 0; rt < 2; ++rt)
        #pragma unroll
        for (int r = 0; r < 4; ++r) {
            const float ri = s_rsinv[rt*16 + g*4 + r];
            float S = 0.f;
            #pragma unroll
            for (int t = 0; t < 16; ++t) {
                float soft = acc[rt][t][r] * ri;
                float sh = soft - THRES;
                float v = 0.f;
                if (sh > 0.f) v = sh * soft / (sh + FEPS);   // rare: ~2/2048 cols
                acc[rt][t][r] = v; S += v;
            }
            #pragma unroll
            for (int off = 8; off >= 1; off >>= 1) S += __shfl_xor(S, off);
            if (m == 0) s_red[wv][rt*16 + g*4 + r] = S;
        }
    __syncthreads();
    if (tid < BM) {
        float S = s_red[0][tid];
        #pragma unroll
        for (int w = 1; w < 8; ++w) S += s_red[w][tid];
        s_Sinv[tid] = 1.0f / fmaxf(S, FEPS);
    }
    __syncthreads();

    // ---- normalize into acc, top-2 track, survivor scatter (no global store here) ----
    #pragma unroll
    for (int rt = 0; rt < 2; ++rt)
        #pragma unroll
        for (int r = 0; r < 4; ++r) {
            const int lr = rt*16 + g*4 + r;
            const float si = s_Sinv[lr];
            float t1v = -1.f, t2v = -1.f; int t1c = 0x7fffffff, t2c = 0x7fffffff;
            #pragma unroll
            for (int t = 0; t < 16; ++t) {
                const int col = wv*256 + t*16 + m;
                float a = acc[rt][t][r] * si;
                acc[rt][t][r] = a;
                if (a > t1v)      { t2v = t1v; t2c = t1c; t1v = a; t1c = col; }
                else if (a > t2v) { t2v = a;  t2c = col; }
                if (a > 0.f) {
                    int p = atomicAdd(&s_cnt[lr], 1);
                    if (p < MAXS) { s_scol[lr][p] = col; s_sval[lr][p] = a; }
                }
            }
            #pragma unroll
            for (int off = 8; off >= 1; off >>= 1) {
                float o1v = __shfl_xor(t1v, off); int o1c = __shfl_xor(t1c, off);
                float o2v = __shfl_xor(t2v, off); int o2c = __shfl_xor(t2c, off);
                bool ob = (o1v > t1v) || (o1v == t1v && o1c < t1c);
                float n1v = ob ? o1v : t1v; int n1c = ob ? o1c : t1c;
                float c1v = ob ? t1v : o1v; int c1c = ob ? t1c : o1c;
                float c2v = ob ? o2v : t2v; int c2c = ob ? o2c : t2c;
                bool sb = (c1v > c2v) || (c1v == c2v && c1c < c2c);
                t1v = n1v; t1c = n1c;
                t2v = sb ? c1v : c2v; t2c = sb ? c1c : c2c;
            }
            if (m == 0) {
                s_t1v[wv][lr] = t1v; s_t1c[wv][lr] = t1c;
                s_t2v[wv][lr] = t2v; s_t2c[wv][lr] = t2c;
            }
        }
    __syncthreads();
    if (tid < BM) {
        float b1v = s_t1v[0][tid]; int b1c = s_t1c[0][tid];
        float b2v = s_t2v[0][tid]; int b2c = s_t2c[0][tid];
        #pragma unroll
        for (int w = 1; w < 8; ++w) {
            float o1v = s_t1v[w][tid]; int o1c = s_t1c[w][tid];
            float o2v = s_t2v[w][tid]; int o2c = s_t2c[w][tid];
            bool ob = (o1v > b1v) || (o1v == b1v && o1c < b1c);
            float n1v = ob ? o1v : b1v; int n1c = ob ? o1c : b1c;
            float c1v = ob ? b1v : o1v; int c1c = ob ? b1c : o1c;
            float c2v = ob ? o2v : b2v; int c2c = ob ? o2c : b2c;
            bool sb = (c1v > c2v) || (c1v == c2v && c1c < c2c);
            b1v = n1v; b1c = n1c;
            b2v = sb ? c1v : c2v; b2c = sb ? c1c : c2c;
        }
        s_ind[tid]  = b1c;
        s_ind2[tid] = (b2v > 0.f) ? b2c : 0;   // all-zero runner-up => ref argmax = 0
    }

    // ---- att store: per-wave LDS bounce transpose -> contiguous 1KB nt stores ----
    // phase (rt,r): lane(g,m) holds rows rt*16+g*4+r, cols t*16+m (within wave slice)
    #pragma unroll
    for (int rt = 0; rt < 2; ++rt)
        #pragma unroll
        for (int r = 0; r < 4; ++r) {
            #pragma unroll
            for (int t = 0; t < 16; ++t)
                s_bounce[wv][g][t*16 + m] = acc[rt][t][r];
            __syncthreads();
            #pragma unroll
            for (int j = 0; j < 4; ++j) {
                f32x4 v = *(const f32x4*)&s_bounce[wv][j][lane*4];
                const int grow = row0 + rt*16 + 4*j + r;
                __builtin_nontemporal_store(v,
                    (f32x4*)(o_att + (size_t)grow * LAN + wv*256 + lane*4));
            }
            __syncthreads();
        }

    // ---- per-row finals: sparse att@W, nl, nl2, col ----
    #pragma unroll
    for (int u = 0; u < 4; ++u) {
        const int lr = wv*4 + u;
        const int grow = row0 + lr;
        const int d0 = lane * 2;
        const int cnt = min(s_cnt[lr], MAXS);
        float o0 = 0.f, o1 = 0.f;
        for (int s2 = 0; s2 < cnt; ++s2) {
            const int c = s_scol[lr][s2];
            const float v = s_sval[lr][s2];
            const float2 w2 = *(const float2*)(W + (size_t)c * FEA + d0);
            o0 += v * w2.x; o1 += v * w2.y;
        }
        __builtin_nontemporal_store((f32x2v){o0, o1},
            (f32x2v*)(o_out + (size_t)grow * FEA + d0));
        const int i1 = s_ind[lr], i2 = s_ind2[lr];
        const float2 w1 = *(const float2*)(W + (size_t)i1 * FEA + d0);
        const float2 w2 = *(const float2*)(W + (size_t)i2 * FEA + d0);
        __builtin_nontemporal_store((f32x2v){w1.x, w1.y},
            (f32x2v*)(o_nl  + (size_t)grow * FEA + d0));
        __builtin_nontemporal_store((f32x2v){w2.x, w2.y},
            (f32x2v*)(o_nl2 + (size_t)grow * FEA + d0));
        float x0 = (float)s_ah[lr][d0]     + (float)s_al[lr][d0];
        float x1 = (float)s_ah[lr][d0 + 1] + (float)s_al[lr][d0 + 1];
        float dx0 = x0 - cen[d0];
        float dx1 = x1 - cen[d0 + 1];
        float dd = dx0 * dx0 + dx1 * dx1;
        #pragma unroll
        for (int off = 32; off >= 1; off >>= 1) dd += __shfl_xor(dd, off);
        if (lane == 0) o_col[grow] = (sqrtf(dd) < 1.0f) ? 1.0f : 0.0f;
    }
}

extern "C" void kernel_launch(void* const* d_in, const int* in_sizes, int n_in,
                              void* d_out, int out_size, void* d_ws, size_t ws_size,
                              hipStream_t stream) {
    const float* X = (const float*)d_in[0];
    const float* W = (const float*)d_in[1];

    _Float16* Wh = (_Float16*)d_ws;                       // 512 KB
    _Float16* Wl = Wh + (size_t)LAN * FEA;                // 512 KB
    float*    cen = (float*)(Wl + (size_t)LAN * FEA);     // 512 B

    float* out      = (float*)d_out;
    float* o_output = out;
    float* o_att    = o_output + (size_t)NS * FEA;
    float* o_nl     = o_att    + (size_t)NS * LAN;
    float* o_nl2    = o_nl     + (size_t)NS * FEA;
    float* o_col    = o_nl2    + (size_t)NS * FEA;

    k_prep_w<<<(LAN * FEA) / 256, 256, 0, stream>>>(W, Wh, Wl);
    k_cen<<<FEA, 256, 0, stream>>>(W, cen);
    k_main<<<NS / BM, 512, 0, stream>>>(X, W, Wh, Wl, cen,
                                        o_output, o_att, o_nl, o_nl2, o_col);
}

// Round 4
// 442.787 us; speedup vs baseline: 3.7043x; 3.7043x over previous
//
#include <hip/hip_runtime.h>
#include <math.h>

#define NS 65536
#define LAN 2048
#define FEA 128

constexpr float THRES = 0.0025f;
constexpr float FEPS  = 1e-12f;
constexpr int BM   = 32;    // rows per block
constexpr int MAXS = 160;   // survivors/row cap (observed ~2-4; dropped-survivor error ~1e-4 anyway)

typedef _Float16 half8 __attribute__((ext_vector_type(8)));
typedef float    f32x4 __attribute__((ext_vector_type(4)));

// ---- prep: split W (fp32) into f16 high/low parts, row-major [2048][128] ----
__global__ void k_prep_w(const float* __restrict__ W,
                         _Float16* __restrict__ Wh, _Float16* __restrict__ Wl) {
    int i = blockIdx.x * 256 + threadIdx.x;
    float w = W[i];
    _Float16 h = (_Float16)w;
    Wh[i] = h;
    Wl[i] = (_Float16)(w - (float)h);
}

// ---- cen[k] = mean_c W[c][k] ----
__global__ void k_cen(const float* __restrict__ W, float* __restrict__ cen) {
    __shared__ float sb[4];
    int k = blockIdx.x;
    int tid = threadIdx.x;
    float s = 0.f;
    for (int c = tid; c < LAN; c += 256) s += W[(size_t)c * FEA + k];
    #pragma unroll
    for (int off = 32; off >= 1; off >>= 1) s += __shfl_xor(s, off);
    if ((tid & 63) == 0) sb[tid >> 6] = s;
    __syncthreads();
    if (tid == 0) cen[k] = (sb[0] + sb[1] + sb[2] + sb[3]) * (1.0f / (float)LAN);
}

// ---- col mask: ||x - cen|| < 1.0, one wave per row ----
__global__ void k_col(const float* __restrict__ X, const float* __restrict__ cen,
                      float* __restrict__ o_col) {
    const int wv = threadIdx.x >> 6, lane = threadIdx.x & 63;
    const int row = blockIdx.x * 4 + wv;
    const float2 x2 = *(const float2*)(X + (size_t)row * FEA + lane * 2);
    float dx0 = x2.x - cen[lane * 2];
    float dx1 = x2.y - cen[lane * 2 + 1];
    float dd = dx0 * dx0 + dx1 * dx1;
    #pragma unroll
    for (int off = 32; off >= 1; off >>= 1) dd += __shfl_xor(dd, off);
    if (lane == 0) o_col[row] = (sqrtf(dd) < 1.0f) ? 1.0f : 0.0f;
}

__device__ static inline void gload_lds16(const void* g, void* l) {
    __builtin_amdgcn_global_load_lds(
        (const __attribute__((address_space(1))) void*)g,
        (__attribute__((address_space(3))) void*)l, 16, 0, 0);
}

// ---- main fused kernel: 512 threads (8 waves), 32 rows x 2048 cols per block ----
// wave wv owns all 32 rows x cols [wv*256, wv*256+256)
// MFMA 16x16x32_f16, 3-term split. C-frag: row=(lane>>4)*4+r, col=lane&15.
__global__ __launch_bounds__(512, 2) void k_main(
    const float* __restrict__ X, const float* __restrict__ W,
    const _Float16* __restrict__ Wh, const _Float16* __restrict__ Wl,
    float* __restrict__ o_out, float* __restrict__ o_att,
    float* __restrict__ o_nl, float* __restrict__ o_nl2)
{
    // pool reuse: [X-stage 16K] -> [B-tiles 2buf x 8waves x 8K = 128K] -> [bounce 33.8K | scol 20K @40960]
    __shared__ __align__(16) char s_pool[131072];
    __shared__ float s_sval[BM][MAXS];
    __shared__ float s_red[8][BM];
    __shared__ float s_t1v[8][BM]; __shared__ int s_t1c[8][BM];
    __shared__ float s_t2v[8][BM]; __shared__ int s_t2c[8][BM];
    __shared__ float s_rmax[BM], s_rsinv[BM], s_Sinv[BM];
    __shared__ int   s_ind[BM], s_ind2[BM], s_cnt[BM];

    const int tid  = threadIdx.x;
    const int wv   = tid >> 6;
    const int lane = tid & 63;
    const int g    = lane >> 4;
    const int m    = lane & 15;
    const int row0 = blockIdx.x * BM;

    // ---- stage X fp32 tile into pool, XOR-swizzled (16B granule) ----
    {
        const f32x4* xsrc = (const f32x4*)(X + (size_t)row0 * FEA);
        #pragma unroll
        for (int q = 0; q < 2; ++q) {
            int idx = tid + q * 512;              // f32x4 index 0..1023
            f32x4 v = xsrc[idx];
            int r = idx >> 5, slot = idx & 31;    // 32 x 16B per row
            int byt = (r * 512 + slot * 16) ^ ((r & 7) << 4);
            *(f32x4*)(s_pool + byt) = v;
        }
    }
    __syncthreads();

    // ---- build A fragments (f16 split) from staged X ----
    half8 afh[2][4], afl[2][4];
    #pragma unroll
    for (int rt = 0; rt < 2; ++rt)
        #pragma unroll
        for (int kb = 0; kb < 4; ++kb) {
            const int r = rt * 16 + m;
            int b0 = (r * 512 + (kb * 8 + g * 2 + 0) * 16) ^ ((r & 7) << 4);
            int b1 = (r * 512 + (kb * 8 + g * 2 + 1) * 16) ^ ((r & 7) << 4);
            f32x4 xa = *(const f32x4*)(s_pool + b0);
            f32x4 xb = *(const f32x4*)(s_pool + b1);
            half8 h, l;
            #pragma unroll
            for (int e = 0; e < 4; ++e) {
                _Float16 hh = (_Float16)xa[e];
                h[e] = hh; l[e] = (_Float16)(xa[e] - (float)hh);
            }
            #pragma unroll
            for (int e = 0; e < 4; ++e) {
                _Float16 hh = (_Float16)xb[e];
                h[4 + e] = hh; l[4 + e] = (_Float16)(xb[e] - (float)hh);
            }
            afh[rt][kb] = h; afl[rt][kb] = l;
        }
    __syncthreads();   // X-stage region now free for B-tile DMA

    f32x4 acc[2][16];
    #pragma unroll
    for (int rt = 0; rt < 2; ++rt)
        #pragma unroll
        for (int t = 0; t < 16; ++t) acc[rt][t] = (f32x4){0.f, 0.f, 0.f, 0.f};

    // ---- GEMM: 16 col-steps, wave-private LDS B-tiles, double-buffered DMA ----
    // LDS tile (per wave, per half): rows 0..15 (= cols of this step), 256B each.
    // DMA dest linear; source pre-swizzled chunk gc = c ^ ((c>>4)&7)
    // read: byte = (m*256 + kb*64 + g*16) ^ ((m&7)<<4)
    #define ISSUE_B(t_, buf_)                                                        \
        {                                                                            \
            const char* gh_ = (const char*)(Wh + (size_t)(wv * 256 + (t_) * 16) * FEA); \
            const char* gl_ = (const char*)(Wl + (size_t)(wv * 256 + (t_) * 16) * FEA); \
            char* lb_ = s_pool + (buf_) * 65536 + wv * 8192;                         \
            _Pragma("unroll")                                                        \
            for (int i_ = 0; i_ < 4; ++i_) {                                         \
                int c_ = i_ * 64 + lane;                                             \
                int gc_ = c_ ^ ((c_ >> 4) & 7);                                      \
                gload_lds16(gh_ + gc_ * 16, lb_ + i_ * 1024);                        \
                gload_lds16(gl_ + gc_ * 16, lb_ + 4096 + i_ * 1024);                 \
            }                                                                        \
        }

    ISSUE_B(0, 0)
    #pragma unroll 16
    for (int t = 0; t < 16; ++t) {
        const int buf = t & 1;
        if (t < 15) {
            ISSUE_B(t + 1, buf ^ 1)
            asm volatile("s_waitcnt vmcnt(8)" ::: "memory");
        } else {
            asm volatile("s_waitcnt vmcnt(0)" ::: "memory");
        }
        __builtin_amdgcn_sched_barrier(0);
        const char* bb = s_pool + buf * 65536 + wv * 8192;
        half8 bh[4], bl[4];
        #pragma unroll
        for (int kb = 0; kb < 4; ++kb) {
            int off = (m * 256 + kb * 64 + g * 16) ^ ((m & 7) << 4);
            bh[kb] = *(const half8*)(bb + off);
            bl[kb] = *(const half8*)(bb + 4096 + off);
        }
        asm volatile("s_waitcnt lgkmcnt(0)" ::: "memory");
        __builtin_amdgcn_sched_barrier(0);
        #pragma unroll
        for (int kb = 0; kb < 4; ++kb)
            #pragma unroll
            for (int rt = 0; rt < 2; ++rt) {
                acc[rt][t] = __builtin_amdgcn_mfma_f32_16x16x32_f16(afh[rt][kb], bh[kb], acc[rt][t], 0, 0, 0);
                acc[rt][t] = __builtin_amdgcn_mfma_f32_16x16x32_f16(afl[rt][kb], bh[kb], acc[rt][t], 0, 0, 0);
                acc[rt][t] = __builtin_amdgcn_mfma_f32_16x16x32_f16(afh[rt][kb], bl[kb], acc[rt][t], 0, 0, 0);
            }
    }
    #undef ISSUE_B

    // lane's row for (rt, r): lr = rt*16 + g*4 + r ; col for t: wv*256 + t*16 + m

    // ---- row max ----
    #pragma unroll
    for (int rt = 0; rt < 2; ++rt)
        #pragma unroll
        for (int r = 0; r < 4; ++r) {
            float mx = acc[rt][0][r];
            #pragma unroll
            for (int t = 1; t < 16; ++t) mx = fmaxf(mx, acc[rt][t][r]);
            #pragma unroll
            for (int off = 8; off >= 1; off >>= 1) mx = fmaxf(mx, __shfl_xor(mx, off));
            if (m == 0) s_red[wv][rt*16 + g*4 + r] = mx;
        }
    __syncthreads();
    if (tid < BM) {
        float mx = s_red[0][tid];
        #pragma unroll
        for (int w = 1; w < 8; ++w) mx = fmaxf(mx, s_red[w][tid]);
        s_rmax[tid] = mx;
    }
    __syncthreads();

    // ---- exp + row sum ----
    #pragma unroll
    for (int rt = 0; rt < 2; ++rt)
        #pragma unroll
        for (int r = 0; r < 4; ++r) {
            const float rm = s_rmax[rt*16 + g*4 + r];
            float s = 0.f;
            #pragma unroll
            for (int t = 0; t < 16; ++t) {
                float e = expf(acc[rt][t][r] - rm);
                acc[rt][t][r] = e; s += e;
            }
            #pragma unroll
            for (int off = 8; off >= 1; off >>= 1) s += __shfl_xor(s, off);
            if (m == 0) s_red[wv][rt*16 + g*4 + r] = s;
        }
    __syncthreads();
    if (tid < BM) {
        float s = s_red[0][tid];
        #pragma unroll
        for (int w = 1; w < 8; ++w) s += s_red[w][tid];
        s_rsinv[tid] = 1.0f / s;      // sum >= 1 always
        s_cnt[tid] = 0;
    }
    __syncthreads();

    // ---- shrink, row S ----
    #pragma unroll
    for (int rt = 0; rt < 2; ++rt)
        #pragma unroll
        for (int r = 0; r < 4; ++r) {
            const float ri = s_rsinv[rt*16 + g*4 + r];
            float S = 0.f;
            #pragma unroll
            for (int t = 0; t < 16; ++t) {
                float soft = acc[rt][t][r] * ri;
                float sh = soft - THRES;
                float v = 0.f;
                if (sh > 0.f) v = sh * soft / (sh + FEPS);
                acc[rt][t][r] = v; S += v;
            }
            #pragma unroll
            for (int off = 8; off >= 1; off >>= 1) S += __shfl_xor(S, off);
            if (m == 0) s_red[wv][rt*16 + g*4 + r] = S;
        }
    __syncthreads();
    if (tid < BM) {
        float S = s_red[0][tid];
        #pragma unroll
        for (int w = 1; w < 8; ++w) S += s_red[w][tid];
        s_Sinv[tid] = 1.0f / fmaxf(S, FEPS);
    }
    __syncthreads();

    // ---- normalize into acc, top-2 track, survivor scatter ----
    int* s_scol = (int*)(s_pool + 40960);      // [BM][MAXS], B-tiles dead now
    #pragma unroll
    for (int rt = 0; rt < 2; ++rt)
        #pragma unroll
        for (int r = 0; r < 4; ++r) {
            const int lr = rt*16 + g*4 + r;
            const float si = s_Sinv[lr];
            float t1v = -1.f, t2v = -1.f; int t1c = 0x7fffffff, t2c = 0x7fffffff;
            #pragma unroll
            for (int t = 0; t < 16; ++t) {
                const int col = wv*256 + t*16 + m;
                float a = acc[rt][t][r] * si;
                acc[rt][t][r] = a;
                if (a > t1v)      { t2v = t1v; t2c = t1c; t1v = a; t1c = col; }
                else if (a > t2v) { t2v = a;  t2c = col; }
                if (a > 0.f) {
                    int p = atomicAdd(&s_cnt[lr], 1);
                    if (p < MAXS) { s_scol[lr*MAXS + p] = col; s_sval[lr][p] = a; }
                }
            }
            #pragma unroll
            for (int off = 8; off >= 1; off >>= 1) {
                float o1v = __shfl_xor(t1v, off); int o1c = __shfl_xor(t1c, off);
                float o2v = __shfl_xor(t2v, off); int o2c = __shfl_xor(t2c, off);
                bool ob = (o1v > t1v) || (o1v == t1v && o1c < t1c);
                float n1v = ob ? o1v : t1v; int n1c = ob ? o1c : t1c;
                float c1v = ob ? t1v : o1v; int c1c = ob ? t1c : o1c;
                float c2v = ob ? o2v : t2v; int c2c = ob ? o2c : t2c;
                bool sb = (c1v > c2v) || (c1v == c2v && c1c < c2c);
                t1v = n1v; t1c = n1c;
                t2v = sb ? c1v : c2v; t2c = sb ? c1c : c2c;
            }
            if (m == 0) {
                s_t1v[wv][lr] = t1v; s_t1c[wv][lr] = t1c;
                s_t2v[wv][lr] = t2v; s_t2c[wv][lr] = t2c;
            }
        }
    __syncthreads();
    if (tid < BM) {
        float b1v = s_t1v[0][tid]; int b1c = s_t1c[0][tid];
        float b2v = s_t2v[0][tid]; int b2c = s_t2c[0][tid];
        #pragma unroll
        for (int w = 1; w < 8; ++w) {
            float o1v = s_t1v[w][tid]; int o1c = s_t1c[w][tid];
            float o2v = s_t2v[w][tid]; int o2c = s_t2c[w][tid];
            bool ob = (o1v > b1v) || (o1v == b1v && o1c < b1c);
            float n1v = ob ? o1v : b1v; int n1c = ob ? o1c : b1c;
            float c1v = ob ? b1v : o1v; int c1c = ob ? b1c : o1c;
            float c2v = ob ? o2v : b2v; int c2c = ob ? o2c : b2c;
            bool sb = (c1v > c2v) || (c1v == c2v && c1c < c2c);
            b1v = n1v; b1c = n1c;
            b2v = sb ? c1v : c2v; b2c = sb ? c1c : c2c;
        }
        s_ind[tid]  = b1c;
        s_ind2[tid] = (b2v > 0.f) ? b2c : 0;
    }
    __syncthreads();

    // ---- att store: wave-local LDS bounce -> contiguous 1KB plain stores ----
    float* s_bounce = (float*)s_pool;          // [8 waves][4][264] floats = 33792 B
    #pragma unroll
    for (int rt = 0; rt < 2; ++rt)
        #pragma unroll
        for (int r = 0; r < 4; ++r) {
            #pragma unroll
            for (int t = 0; t < 16; ++t)
                s_bounce[wv*1056 + g*264 + t*16 + m] = acc[rt][t][r];
            asm volatile("s_waitcnt lgkmcnt(0)" ::: "memory");
            __builtin_amdgcn_sched_barrier(0);
            #pragma unroll
            for (int j = 0; j < 4; ++j) {
                f32x4 v = *(const f32x4*)&s_bounce[wv*1056 + j*264 + lane*4];
                const int grow = row0 + rt*16 + 4*j + r;
                *(f32x4*)(o_att + (size_t)grow * LAN + wv*256 + lane*4) = v;
            }
            asm volatile("s_waitcnt lgkmcnt(0)" ::: "memory");
            __builtin_amdgcn_sched_barrier(0);
        }

    // ---- per-row finals: sparse att@W, nl, nl2 ----
    #pragma unroll
    for (int u = 0; u < 4; ++u) {
        const int lr = wv*4 + u;
        const int grow = row0 + lr;
        const int d0 = lane * 2;
        const int cnt = min(s_cnt[lr], MAXS);
        float o0 = 0.f, o1 = 0.f;
        for (int s2 = 0; s2 < cnt; ++s2) {
            const int c = s_scol[lr*MAXS + s2];
            const float v = s_sval[lr][s2];
            const float2 w2 = *(const float2*)(W + (size_t)c * FEA + d0);
            o0 += v * w2.x; o1 += v * w2.y;
        }
        *(float2*)(o_out + (size_t)grow * FEA + d0) = make_float2(o0, o1);
        const int i1 = s_ind[lr], i2 = s_ind2[lr];
        *(float2*)(o_nl  + (size_t)grow * FEA + d0) = *(const float2*)(W + (size_t)i1 * FEA + d0);
        *(float2*)(o_nl2 + (size_t)grow * FEA + d0) = *(const float2*)(W + (size_t)i2 * FEA + d0);
    }
}

extern "C" void kernel_launch(void* const* d_in, const int* in_sizes, int n_in,
                              void* d_out, int out_size, void* d_ws, size_t ws_size,
                              hipStream_t stream) {
    const float* X = (const float*)d_in[0];
    const float* W = (const float*)d_in[1];

    _Float16* Wh = (_Float16*)d_ws;                       // 512 KB
    _Float16* Wl = Wh + (size_t)LAN * FEA;                // 512 KB
    float*    cen = (float*)(Wl + (size_t)LAN * FEA);     // 512 B

    float* out      = (float*)d_out;
    float* o_output = out;
    float* o_att    = o_output + (size_t)NS * FEA;
    float* o_nl     = o_att    + (size_t)NS * LAN;
    float* o_nl2    = o_nl     + (size_t)NS * FEA;
    float* o_col    = o_nl2    + (size_t)NS * FEA;

    k_prep_w<<<(LAN * FEA) / 256, 256, 0, stream>>>(W, Wh, Wl);
    k_cen<<<FEA, 256, 0, stream>>>(W, cen);
    k_col<<<NS / 4, 256, 0, stream>>>(X, cen, o_col);
    k_main<<<NS / BM, 512, 0, stream>>>(X, W, Wh, Wl,
                                        o_output, o_att, o_nl, o_nl2);
}